// Round 4
// baseline (115.651 us; speedup 1.0000x reference)
//
#include <hip/hip_runtime.h>
#include <hip/hip_bf16.h>
#include <cstddef>

typedef __attribute__((ext_vector_type(8))) short bf16x8;
typedef __attribute__((ext_vector_type(4))) float f32x4;

#define NCH_ 512
#define NRM_ 0.35355339059327373f  // 64^-0.25
#define RATIO_ 0.0625f             // 256^-0.5
#define EPSC_ 6.25e-6f             // RATIO_*1e-4 (k' eps, applied analytically)
#define MFMA(a,b,c) __builtin_amdgcn_mfma_f32_16x16x32_bf16((a),(b),(c),0,0,0)

__device__ __forceinline__ unsigned short f2b(float f) {
  unsigned u = __float_as_uint(f);
  u += 0x7FFFu + ((u >> 16) & 1u);
  return (unsigned short)(u >> 16);
}
__device__ __forceinline__ float b2f(unsigned short h) {
  return __uint_as_float(((unsigned)h) << 16);
}
__device__ __forceinline__ unsigned pk2f(float a, float b) {
  union { __hip_bfloat162 h; unsigned u; } cv;
  cv.h = __float22bfloat162_rn(make_float2(a, b));
  return cv.u;
}
__device__ __forceinline__ float sumsq4(float4 a){ return a.x*a.x+a.y*a.y+a.z*a.z+a.w*a.w; }

// K1 "front": full feature front-end ONCE. Computes q' and Gr, spills both
// (bf16 [64][256] row-major, 32 KB each) to global scratch so the back kernel
// never recomputes staging/GEMM/exp. Also produces kvxP (chunk-sum C2L),
// blockmax, vsumG. No fences, no spins — kernel boundary is the only flush.
__global__ __launch_bounds__(512, 4) void front_kernel(
    const float* __restrict__ qg, const float* __restrict__ kg,
    const float* __restrict__ vg, const float* __restrict__ projg,
    unsigned short* __restrict__ kvxP,
    unsigned short* __restrict__ qSg, unsigned short* __restrict__ grSg,
    float* __restrict__ blockmax, float* __restrict__ vsumG)
{
  __shared__ unsigned short R0[256*72];   // proj -> qS -> kpS
  __shared__ unsigned short XB[128*72];   // KX|QX -> kpT[128][72]
  __shared__ unsigned short C_[80*72];    // vext [c][s]
  __shared__ float diagK[64];
  __shared__ float diagQ[64];
  __shared__ float rmS[8*64];
  __shared__ float cmS[8];
  const int t=threadIdx.x, ch=blockIdx.x;
  const int row0 = ch*64;
  const int lane=t&63, m16=lane&15, q4=lane>>4, w=t>>6;   // w 0..7
  const int f0 = w*32;          // 32 proj-features per wave
  const int g  = w>>2;
  unsigned short* KX = XB;
  unsigned short* QX = XB + 64*72;
  unsigned short* kpT = XB;

  // ---- staging ----
#pragma unroll
  for (int i=0;i<4;++i){ int flat=i*4096+t*8; int f=flat>>6, d2=flat&63;
    float4 p0 = *(const float4*)(projg+flat);
    float4 p1 = *(const float4*)(projg+flat+4);
    *(uint4*)&R0[f*72+d2] = make_uint4(pk2f(p0.x,p0.y),pk2f(p0.z,p0.w),
                                       pk2f(p1.x,p1.y),pk2f(p1.z,p1.w)); }
  {  // k staging (bf16, scaled) + diagK
    const float* xg = kg + (size_t)row0*64;
#pragma unroll
    for (int i=0;i<2;++i){
      int flat=i*2048+t*4; int r=flat>>6, d2=flat&63;
      float4 f = *(const float4*)(xg+flat);
      float ss = sumsq4(f);
      ss += __shfl_xor(ss,1); ss += __shfl_xor(ss,2);
      ss += __shfl_xor(ss,4); ss += __shfl_xor(ss,8);
      if ((t&15)==0) diagK[r] = 0.0625f*ss;
      *(uint2*)&KX[r*72+d2] = make_uint2(pk2f(NRM_*f.x,NRM_*f.y), pk2f(NRM_*f.z,NRM_*f.w));
    }
  }
  {  // q staging + diagQ
    const float* xg = qg + (size_t)row0*64;
#pragma unroll
    for (int i=0;i<2;++i){
      int flat=i*2048+t*4; int r=flat>>6, d2=flat&63;
      float4 f = *(const float4*)(xg+flat);
      float ss = sumsq4(f);
      ss += __shfl_xor(ss,1); ss += __shfl_xor(ss,2);
      ss += __shfl_xor(ss,4); ss += __shfl_xor(ss,8);
      if ((t&15)==0) diagQ[r] = 0.0625f*ss;
      *(uint2*)&QX[r*72+d2] = make_uint2(pk2f(NRM_*f.x,NRM_*f.y), pk2f(NRM_*f.z,NRM_*f.w));
    }
  }
  {  // vext staging
    int c = t&63, sq_ = t>>6;
#pragma unroll
    for (int i=0;i<8;++i)
      C_[c*72 + sq_*8 + i] = f2b(vg[((size_t)row0 + sq_*8 + i)*64 + c]);
    if (t < 256) {
      int cc = 64 + (t>>4), s4 = (t&15)*4;
      unsigned short hv = (cc==64) ? (unsigned short)0x3F80 : (unsigned short)0;
      unsigned pv = (unsigned)hv | ((unsigned)hv<<16);
      *(uint2*)&C_[cc*72 + s4] = make_uint2(pv, pv);
    }
  }
  __syncthreads();

  if (t < 80) {   // vsum = colsum(Vext)
    float s = 0.f;
#pragma unroll 16
    for (int i=0;i<64;++i) s += b2f(C_[t*72+i]);
    vsumG[(size_t)ch*80 + t] = s;
  }

  // ---- feature GEMMs (k pass, q pass) ----
  float dk4[4], dq4[4];
#pragma unroll
  for (int rt=0;rt<4;++rt){ dk4[rt] = diagK[rt*16+m16]; dq4[rt] = diagQ[rt*16+m16]; }
  f32x4 kacc[4][2], qacc[4][2];
#pragma unroll
  for (int rt=0;rt<4;++rt)
#pragma unroll
    for (int mt=0;mt<2;++mt){ kacc[rt][mt] = (f32x4){0.f,0.f,0.f,0.f};
                              qacc[rt][mt] = (f32x4){0.f,0.f,0.f,0.f}; }
  {
    bf16x8 bk[4][2];
#pragma unroll
    for (int rt=0;rt<4;++rt){
      bk[rt][0] = *(const bf16x8*)&KX[(rt*16+m16)*72 + q4*8];
      bk[rt][1] = *(const bf16x8*)&KX[(rt*16+m16)*72 + 32 + q4*8];
    }
#pragma unroll
    for (int kk=0;kk<2;++kk)
#pragma unroll
      for (int mt=0;mt<2;++mt){
        bf16x8 a = *(const bf16x8*)&R0[(f0+mt*16+m16)*72 + kk*32 + q4*8];
#pragma unroll
        for (int rt=0;rt<4;++rt)
          kacc[rt][mt] = MFMA(a, bk[rt][kk], kacc[rt][mt]);
      }
  }
  {
    bf16x8 bq[4][2];
#pragma unroll
    for (int rt=0;rt<4;++rt){
      bq[rt][0] = *(const bf16x8*)&QX[(rt*16+m16)*72 + q4*8];
      bq[rt][1] = *(const bf16x8*)&QX[(rt*16+m16)*72 + 32 + q4*8];
    }
#pragma unroll
    for (int kk=0;kk<2;++kk)
#pragma unroll
      for (int mt=0;mt<2;++mt){
        bf16x8 a = *(const bf16x8*)&R0[(f0+mt*16+m16)*72 + kk*32 + q4*8];
#pragma unroll
        for (int rt=0;rt<4;++rt)
          qacc[rt][mt] = MFMA(a, bq[rt][kk], qacc[rt][mt]);
      }
  }
  {  // k chunk max
    float mx = kacc[0][0][0];
#pragma unroll
    for (int rt=0;rt<4;++rt)
#pragma unroll
      for (int mt=0;mt<2;++mt)
#pragma unroll
        for (int j=0;j<4;++j) mx = fmaxf(mx, kacc[rt][mt][j]);
#pragma unroll
    for (int off=1; off<64; off<<=1) mx = fmaxf(mx, __shfl_xor(mx, off));
    if (lane == 0) cmS[w] = mx;
  }
#pragma unroll
  for (int rt=0;rt<4;++rt){   // q per-row max (per-wave slice)
    float p = qacc[rt][0][0];
#pragma unroll
    for (int mt=0;mt<2;++mt)
#pragma unroll
      for (int j=0;j<4;++j) p = fmaxf(p, qacc[rt][mt][j]);
    p = fmaxf(p, __shfl_xor(p,16)); p = fmaxf(p, __shfl_xor(p,32));
    if (q4 == 0) rmS[w*64 + rt*16+m16] = p;
  }
  __syncthreads();   // reductions ready; proj/KX/QX reads done
  float cmax = cmS[0];
#pragma unroll
  for (int s=1;s<8;++s) cmax = fmaxf(cmax, cmS[s]);
  if (t == 0) blockmax[ch] = cmax;

  // ---- q' -> qS (R0 overlay) -> spill to qSg ----
  unsigned short* qS = R0;
#pragma unroll
  for (int rt=0;rt<4;++rt){
    int rr = rt*16+m16;
    float rm = rmS[rr];
#pragma unroll
    for (int s=1;s<8;++s) rm = fmaxf(rm, rmS[s*64+rr]);
    float e = dq4[rt] + rm;
#pragma unroll
    for (int mt=0;mt<2;++mt){
      float v0 = RATIO_*(__expf(qacc[rt][mt][0]-e)+1e-4f);
      float v1 = RATIO_*(__expf(qacc[rt][mt][1]-e)+1e-4f);
      float v2 = RATIO_*(__expf(qacc[rt][mt][2]-e)+1e-4f);
      float v3 = RATIO_*(__expf(qacc[rt][mt][3]-e)+1e-4f);
      *(uint2*)&qS[rr*264 + f0 + mt*16 + q4*4] = make_uint2(pk2f(v0,v1), pk2f(v2,v3));
    }
  }
  __syncthreads();
#pragma unroll
  for (int i=0;i<4;++i){ int idx=i*4096+t*8; int r=idx>>8, c=idx&255;
    *(uint4*)&qSg[(size_t)ch*16384 + idx] = *(const uint4*)&qS[r*264+c]; }
  __syncthreads();   // spill reads done; qS dead

  // ---- Gr -> kpS (R0 overlay) + kpT pass 0 ----
  unsigned short* kpS = R0;
  unsigned kpx[4][2][2];
#pragma unroll
  for (int rt=0;rt<4;++rt){
    float e = dk4[rt] + cmax;
    int rr = rt*16+m16;
#pragma unroll
    for (int mt=0;mt<2;++mt){
      float v0 = RATIO_*__expf(kacc[rt][mt][0]-e);
      float v1 = RATIO_*__expf(kacc[rt][mt][1]-e);
      float v2 = RATIO_*__expf(kacc[rt][mt][2]-e);
      float v3 = RATIO_*__expf(kacc[rt][mt][3]-e);
      kpx[rt][mt][0] = pk2f(v0,v1); kpx[rt][mt][1] = pk2f(v2,v3);
      *(uint2*)&kpS[rr*264 + f0 + mt*16 + q4*4] = make_uint2(kpx[rt][mt][0], kpx[rt][mt][1]);
    }
  }
  if (g == 0) {   // kpT pass 0: features 0..127 (waves 0-3)
#pragma unroll
    for (int rt=0;rt<4;++rt)
#pragma unroll
      for (int mt=0;mt<2;++mt)
#pragma unroll
        for (int jp=0;jp<2;++jp){
          int frl = (w&3)*32 + mt*16 + q4*4 + jp*2;
          unsigned uv = kpx[rt][mt][jp];
          kpT[frl*72 + rt*16+m16]     = (unsigned short)uv;
          kpT[(frl+1)*72 + rt*16+m16] = (unsigned short)(uv>>16);
        }
  }
  __syncthreads();
  // spill Gr (kpS is complete and persists through the h-loop)
#pragma unroll
  for (int i=0;i<4;++i){ int idx=i*4096+t*8; int r=idx>>8, c=idx&255;
    *(uint4*)&grSg[(size_t)ch*16384 + idx] = *(const uint4*)&kpS[r*264+c]; }

  // ---- chunk-sum GEMM passes -> kvxP (B-frag-packed C2L) ----
#pragma unroll
  for (int h=0; h<2; ++h) {
    if (h == 1) {
      __syncthreads();
      if (g == 1) {   // kpT pass 1: features 128..255 (waves 4-7)
#pragma unroll
        for (int rt=0;rt<4;++rt)
#pragma unroll
          for (int mt=0;mt<2;++mt)
#pragma unroll
            for (int jp=0;jp<2;++jp){
              int frl = (w&3)*32 + mt*16 + q4*4 + jp*2;
              unsigned uv = kpx[rt][mt][jp];
              kpT[frl*72 + rt*16+m16]     = (unsigned short)uv;
              kpT[(frl+1)*72 + rt*16+m16] = (unsigned short)(uv>>16);
            }
      }
      __syncthreads();
    }
    f32x4 c2a[5];
#pragma unroll
    for (int ct=0;ct<5;++ct) c2a[ct] = (f32x4){0.f,0.f,0.f,0.f};
#pragma unroll
    for (int kk=0;kk<2;++kk){
      bf16x8 bv = *(const bf16x8*)&kpT[(w*16+m16)*72 + kk*32 + q4*8];
#pragma unroll
      for (int ct=0;ct<5;++ct){
        bf16x8 av = *(const bf16x8*)&C_[(ct*16+m16)*72 + kk*32 + q4*8];
        c2a[ct] = MFMA(av, bv, c2a[ct]);
      }
    }
#pragma unroll
    for (int ct=0;ct<5;++ct){
      int mtg = h*8 + w;
      int mrow = mtg*16 + m16;
      int fb = (mrow>>5)*512 + ((mrow>>3)&3)*8 + (mrow&7);
      unsigned short* dst = kvxP + (size_t)(ch*5+ct)*4096 + fb + (q4*4)*32;
#pragma unroll
      for (int j=0;j<4;++j)
        dst[j*32] = f2b(c2a[ct][j]);
    }
    if (h == 0) __syncthreads();
  }
}

// K2: exclusive prefix over 32 chunks per bh: contribution = s_chl*C2L + EPSC*vsum.
__global__ __launch_bounds__(256, 4) void scan_kernel(
    const unsigned short* __restrict__ kvxP, unsigned short* __restrict__ sxP,
    const float* __restrict__ blockmax, const float* __restrict__ vsumG)
{
  __shared__ float sS[32];
  __shared__ float vsS[32][16];
  const int t = threadIdx.x, bid = blockIdx.x;   // 0..319
  const int qtr = bid & 3, ct = (bid>>2)%5, bh = bid/20;
  if (t < 32) {
    float bm = blockmax[bh*32 + t];
    float km = bm;
#pragma unroll
    for (int off=16; off>=1; off>>=1) km = fmaxf(km, __shfl_xor(km, off));
    sS[t] = __expf(bm - km);
  }
  for (int i=t; i<512; i+=256){
    int chl = i>>4, c16 = i&15;
    vsS[chl][c16] = vsumG[(size_t)(bh*32+chl)*80 + ct*16 + c16];
  }
  __syncthreads();
  const int fbase = qtr*1024 + t*4;
  const int c16t = (t>>3)&15;
  const bool isEps = (ct==4) && (c16t == 1);
  float carry0=0.f, carry1=0.f, carry2=0.f, carry3=0.f;
  const size_t stride = (size_t)5*4096;
  size_t base = ((size_t)(bh*32)*5 + ct)*4096 + fbase;
#pragma unroll 8
  for (int chl=0; chl<32; ++chl){
    unsigned s0, s1;
    if (isEps) { unsigned ee = pk2f(1e-6f,1e-6f); s0 = ee; s1 = ee; }
    else { s0 = pk2f(carry0,carry1); s1 = pk2f(carry2,carry3); }
    *(uint2*)(sxP + base) = make_uint2(s0, s1);
    uint2 raw = *(const uint2*)(kvxP + base);
    float sch = sS[chl];
    float evs = EPSC_ * vsS[chl][c16t];
    carry0 += sch*b2f((unsigned short)(raw.x))     + evs;
    carry1 += sch*b2f((unsigned short)(raw.x>>16)) + evs;
    carry2 += sch*b2f((unsigned short)(raw.y))     + evs;
    carry3 += sch*b2f((unsigned short)(raw.y>>16)) + evs;
    base += stride;
  }
}

// K3 "back": loads spilled q' and Gr (no recompute), restages vext, then
// accA = Q'@Gr^T (g0 waves) || accO = Q'@Sx (g1 waves), P, P@Vext, output.
__global__ __launch_bounds__(512, 4) void back_kernel(
    const unsigned short* __restrict__ qSg, const unsigned short* __restrict__ grSg,
    const unsigned short* __restrict__ sxP, const float* __restrict__ vg,
    const float* __restrict__ blockmax, float* __restrict__ out_g)
{
  __shared__ unsigned short R0[64*264];   // qS -> kpS -> oT (f32[64][68])
  __shared__ unsigned short P_[64*72];
  __shared__ unsigned short C_[80*72];
  __shared__ float schS;
  const int t=threadIdx.x, ch=blockIdx.x;
  const int row0 = ch*64;
  const int lane=t&63, m16=lane&15, q4=lane>>4, w=t>>6;
  const int rw = (w&3)*16;      // 16-row band (wave pair w, w+4)
  const int g  = w>>2;
  const int bh = ch>>5;

  // ---- vext staging ----
  {
    int c = t&63, sq_ = t>>6;
#pragma unroll
    for (int i=0;i<8;++i)
      C_[c*72 + sq_*8 + i] = f2b(vg[((size_t)row0 + sq_*8 + i)*64 + c]);
    if (t < 256) {
      int cc = 64 + (t>>4), s4 = (t&15)*4;
      unsigned short hv = (cc==64) ? (unsigned short)0x3F80 : (unsigned short)0;
      unsigned pv = (unsigned)hv | ((unsigned)hv<<16);
      *(uint2*)&C_[cc*72 + s4] = make_uint2(pv, pv);
    }
  }
  // ---- q' load -> R0-as-qS ----
#pragma unroll
  for (int i=0;i<4;++i){ int idx=i*4096+t*8; int r=idx>>8, c=idx&255;
    *(uint4*)&R0[r*264+c] = *(const uint4*)&qSg[(size_t)ch*16384 + idx]; }
  if (t < 32) {   // s_ch = exp(cmax_ch - kmax_bh)
    float bm = blockmax[bh*32 + t];
    float km = bm;
#pragma unroll
    for (int off=16; off>=1; off>>=1) km = fmaxf(km, __shfl_xor(km, off));
    if (t == (ch & 31)) schS = __expf(bm - km);
  }
  __syncthreads();
  // ---- aq frags + q1 ----
  bf16x8 aq[8];
#pragma unroll
  for (int kk=0;kk<8;++kk)
    aq[kk] = *(const bf16x8*)&R0[(rw+m16)*264 + kk*32 + q4*8];
  float q1v = 0.f;
#pragma unroll
  for (int kk=0;kk<8;++kk){
    union { bf16x8 v; unsigned u[4]; } av; av.v = aq[kk];
#pragma unroll
    for (int i=0;i<4;++i)
      q1v += b2f((unsigned short)av.u[i]) + b2f((unsigned short)(av.u[i]>>16));
  }
  q1v += __shfl_xor(q1v,16); q1v += __shfl_xor(q1v,32);
  __syncthreads();   // qS dead
  // ---- Gr load -> R0-as-kpS ----
#pragma unroll
  for (int i=0;i<4;++i){ int idx=i*4096+t*8; int r=idx>>8, c=idx&255;
    *(uint4*)&R0[r*264+c] = *(const uint4*)&grSg[(size_t)ch*16384 + idx]; }
  __syncthreads();
  unsigned short* kpS = R0;

  // ---- accA (g0) || accO (g1) ----
  f32x4 accA[4], accO[5];
#pragma unroll
  for (int i=0;i<4;++i) accA[i] = (f32x4){0.f,0.f,0.f,0.f};
#pragma unroll
  for (int i=0;i<5;++i) accO[i] = (f32x4){0.f,0.f,0.f,0.f};
  if (g == 0) {
#pragma unroll
    for (int kk=0;kk<8;++kk){
      bf16x8 a = aq[kk];
#pragma unroll
      for (int st=0;st<4;++st){
        bf16x8 bfr = *(const bf16x8*)&kpS[(st*16+m16)*264 + kk*32 + q4*8];
        accA[st] = MFMA(a, bfr, accA[st]);
      }
    }
  } else {
    const unsigned short* sxb = sxP + (size_t)ch*5*4096 + m16*32 + q4*8;
#pragma unroll
    for (int kk=0;kk<8;++kk){
      bf16x8 a = aq[kk];
#pragma unroll
      for (int ct=0;ct<5;++ct)
        accO[ct] = MFMA(a, *(const bf16x8*)(sxb + (size_t)ct*4096 + kk*512), accO[ct]);
    }
  }
  __syncthreads();   // kpS reads done; schS ready
  const float sch = schS;
  if (g == 0) {   // ---- P = s_ch*AL + EPSC*q1 (masked), rows rw..rw+15 ----
#pragma unroll
    for (int j=0;j<4;++j){
      int rr = rw + q4*4 + j;
      float q1r = __shfl(q1v, q4*4 + j);
      float addc = EPSC_ * q1r;
#pragma unroll
      for (int st=0;st<4;++st){
        int cc = st*16 + m16;
        P_[rr*72 + cc] = f2b((cc<=rr) ? (sch*accA[st][j] + addc) : 0.f);
      }
    }
  }
  __syncthreads();
  if (g == 1) {   // ---- P@Vext + denominator + oT ----
#pragma unroll
    for (int k2=0;k2<2;++k2){
      bf16x8 aP = *(const bf16x8*)&P_[(rw+m16)*72 + k2*32 + q4*8];
#pragma unroll
      for (int ct=0;ct<5;++ct){
        bf16x8 bfr = *(const bf16x8*)&C_[(ct*16+m16)*72 + k2*32 + q4*8];
        accO[ct] = MFMA(aP, bfr, accO[ct]);
      }
    }
    float* oT = (float*)R0;   // kpS dead
#pragma unroll
    for (int j=0;j<4;++j){
      float d64 = __shfl(accO[4][j], (lane & 48));
      float d65 = __shfl(accO[4][j], (lane & 48) | 1);
      float dinv = 1.f/(d64+d65);
      int rr = rw + q4*4 + j;
#pragma unroll
      for (int ct=0;ct<4;++ct)
        oT[rr*68 + ct*16 + m16] = accO[ct][j]*dinv;
    }
  }
  __syncthreads();
  {
    const float* oT = (const float*)R0;
#pragma unroll
    for (int i=0;i<2;++i){ int flat=i*2048+t*4; int r=flat>>6, c2=flat&63;
      *(float4*)(out_g + (size_t)row0*64 + flat) = *(const float4*)&oT[r*68+c2]; }
  }
}

extern "C" void kernel_launch(void* const* d_in, const int* in_sizes, int n_in,
                              void* d_out, int out_size, void* d_ws, size_t ws_size,
                              hipStream_t stream)
{
  (void)in_sizes; (void)n_in; (void)out_size; (void)ws_size;
  const float* q    = (const float*)d_in[0];
  const float* k    = (const float*)d_in[1];
  const float* v    = (const float*)d_in[2];
  const float* proj = (const float*)d_in[3];
  float* out = (float*)d_out;

  char* p8 = (char*)d_ws;
  unsigned short* kvxP = (unsigned short*)p8; p8 += (size_t)NCH_*5*4096*2;  // 20.97 MB
  unsigned short* sxP  = (unsigned short*)p8; p8 += (size_t)NCH_*5*4096*2;  // 20.97 MB
  unsigned short* qSg  = (unsigned short*)p8; p8 += (size_t)NCH_*16384*2;   // 16.78 MB
  unsigned short* grSg = (unsigned short*)p8; p8 += (size_t)NCH_*16384*2;   // 16.78 MB
  float* blockmax = (float*)p8; p8 += NCH_*sizeof(float);
  float* vsumG    = (float*)p8;                                             // 512*80*4B

  front_kernel<<<dim3(NCH_), dim3(512), 0, stream>>>(q, k, v, proj, kvxP,
                                                     qSg, grSg, blockmax, vsumG);
  scan_kernel <<<dim3(320),  dim3(256), 0, stream>>>(kvxP, sxP, blockmax, vsumG);
  back_kernel <<<dim3(NCH_), dim3(512), 0, stream>>>(qSg, grSg, sxP, v,
                                                     blockmax, out);
}